// Round 1
// baseline (608.417 us; speedup 1.0000x reference)
//
#include <hip/hip_runtime.h>
#include <cstdint>

typedef __attribute__((ext_vector_type(8))) short short8;
typedef __attribute__((ext_vector_type(4))) float f32x4;

#define NB 16
#define NT 2048
#define ND 1024
#define NC 512
#define NM (NB*NT)   // 32768 rows

#define BM 64
#define BK 32
#define LDA 40   // padded bf16 row stride (80 B, 16B-aligned, conflict-light)
#define LDB 40

__device__ inline unsigned short f2bf(float f){
  unsigned int u = __float_as_uint(f);
  u += 0x7fffu + ((u >> 16) & 1u);   // RNE; inputs are finite normals
  return (unsigned short)(u >> 16);
}

// ---------------- CAM GEMM + fused softmax (the big kernel) ----------------
// Block: 256 threads (4 waves). Tile: 64 rows x 512 cols (full C -> softmax in-block).
// Each wave: 128-col strip, 4(m) x 8(n) subtiles of 16x16, K staged in BK=32 steps.
__global__ __launch_bounds__(256, 2) void cam_softmax_kernel(
    const float* __restrict__ F,      // [32768,1024]
    const float* __restrict__ W,      // [512,1024]  (row-major = Bt layout, K-contig)
    float* __restrict__ out_soft,     // [32768,512]
    float* __restrict__ out_raw)      // [32768,512]
{
  __shared__ unsigned short As[BM * LDA];   //  5120 B
  __shared__ unsigned short Bs[NC * LDB];   // 40960 B
  __shared__ float redmax[4][BM];
  __shared__ float redsum[4][BM];

  const int tid    = threadIdx.x;
  const int wave   = tid >> 6;
  const int lane   = tid & 63;
  const int lane15 = lane & 15;
  const int quad   = lane >> 4;
  const int m0     = blockIdx.x * BM;

  f32x4 acc[4][8];
  #pragma unroll
  for (int mi = 0; mi < 4; mi++)
    #pragma unroll
    for (int ni = 0; ni < 8; ni++)
      acc[mi][ni] = (f32x4){0.f, 0.f, 0.f, 0.f};

  for (int ks = 0; ks < ND / BK; ks++) {
    const int k0 = ks * BK;
    // ---- stage A: 64x32 fp32 -> bf16 (512 float4, 2/thread, coalesced) ----
    #pragma unroll
    for (int i = 0; i < 2; i++) {
      int j   = tid * 2 + i;
      int row = j >> 3;          // 8 float4 per 32-wide row
      int kq  = j & 7;
      const float4 v = *reinterpret_cast<const float4*>(F + (m0 + row) * ND + k0 + kq * 4);
      ushort4 s4;
      s4.x = f2bf(v.x); s4.y = f2bf(v.y); s4.z = f2bf(v.z); s4.w = f2bf(v.w);
      *reinterpret_cast<ushort4*>(&As[row * LDA + kq * 4]) = s4;
    }
    // ---- stage B: 512x32 fp32 -> bf16 (4096 float4, 16/thread, coalesced) ----
    #pragma unroll
    for (int i = 0; i < 16; i++) {
      int j   = tid + 256 * i;
      int row = j >> 3;
      int kq  = j & 7;
      const float4 v = *reinterpret_cast<const float4*>(W + row * ND + k0 + kq * 4);
      ushort4 s4;
      s4.x = f2bf(v.x); s4.y = f2bf(v.y); s4.z = f2bf(v.z); s4.w = f2bf(v.w);
      *reinterpret_cast<ushort4*>(&Bs[row * LDB + kq * 4]) = s4;
    }
    __syncthreads();

    // ---- MFMA: A frag = A[m=lane15][k=quad*8+j], B frag = W[n=lane15][k=quad*8+j] ----
    short8 afrag[4];
    #pragma unroll
    for (int mi = 0; mi < 4; mi++)
      afrag[mi] = *reinterpret_cast<const short8*>(&As[(mi * 16 + lane15) * LDA + quad * 8]);
    #pragma unroll
    for (int ni = 0; ni < 8; ni++) {
      short8 bfrag = *reinterpret_cast<const short8*>(
          &Bs[(wave * 128 + ni * 16 + lane15) * LDB + quad * 8]);
      #pragma unroll
      for (int mi = 0; mi < 4; mi++)
        acc[mi][ni] = __builtin_amdgcn_mfma_f32_16x16x32_bf16(afrag[mi], bfrag, acc[mi][ni], 0, 0, 0);
    }
    __syncthreads();
  }

  // ---- epilogue: fused softmax over C=512 (4 waves x 128 cols) ----
  // C/D layout: col = lane15, row = quad*4 + reg   [verified m89/m91]
  float rmax[4][4];
  #pragma unroll
  for (int mi = 0; mi < 4; mi++)
    #pragma unroll
    for (int r = 0; r < 4; r++) {
      float m = acc[mi][0][r];
      #pragma unroll
      for (int ni = 1; ni < 8; ni++) m = fmaxf(m, acc[mi][ni][r]);
      #pragma unroll
      for (int off = 1; off < 16; off <<= 1) m = fmaxf(m, __shfl_xor(m, off, 64));
      rmax[mi][r] = m;
    }
  if (lane15 == 0) {
    #pragma unroll
    for (int mi = 0; mi < 4; mi++)
      #pragma unroll
      for (int r = 0; r < 4; r++)
        redmax[wave][mi * 16 + quad * 4 + r] = rmax[mi][r];
  }
  __syncthreads();

  float rsum[4][4];
  #pragma unroll
  for (int mi = 0; mi < 4; mi++)
    #pragma unroll
    for (int r = 0; r < 4; r++) {
      const int row = mi * 16 + quad * 4 + r;
      float m = fmaxf(fmaxf(redmax[0][row], redmax[1][row]),
                      fmaxf(redmax[2][row], redmax[3][row]));
      float s = 0.f;
      #pragma unroll
      for (int ni = 0; ni < 8; ni++) {
        float e = __expf(acc[mi][ni][r] - m);
        acc[mi][ni][r] = e;
        s += e;
      }
      #pragma unroll
      for (int off = 1; off < 16; off <<= 1) s += __shfl_xor(s, off, 64);
      rsum[mi][r] = s;
    }
  if (lane15 == 0) {
    #pragma unroll
    for (int mi = 0; mi < 4; mi++)
      #pragma unroll
      for (int r = 0; r < 4; r++)
        redsum[wave][mi * 16 + quad * 4 + r] = rsum[mi][r];
  }
  __syncthreads();

  #pragma unroll
  for (int mi = 0; mi < 4; mi++)
    #pragma unroll
    for (int r = 0; r < 4; r++) {
      const int row = mi * 16 + quad * 4 + r;
      const float inv = 1.f / (redsum[0][row] + redsum[1][row] + redsum[2][row] + redsum[3][row]);
      const int gr = m0 + row;
      #pragma unroll
      for (int ni = 0; ni < 8; ni++) {
        const int col = wave * 128 + ni * 16 + lane15;
        const float v = acc[mi][ni][r] * inv;
        out_soft[(size_t)gr * NC + col] = v;
        out_raw [(size_t)gr * NC + col] = v;
      }
    }
}

// ---------------- pooled partial sums over T ----------------
__global__ __launch_bounds__(256) void pool_partial_kernel(
    const float* __restrict__ F, float* __restrict__ part)  // part[8][16][1024]
{
  const int d = blockIdx.x * 256 + threadIdx.x;
  const int b = blockIdx.y;
  const int z = blockIdx.z;
  const float* p = F + ((size_t)b * NT + z * 256) * ND + d;
  float s = 0.f;
  #pragma unroll 4
  for (int t = 0; t < 256; t++) s += p[(size_t)t * ND];
  part[(z * NB + b) * ND + d] = s;
}

// ---------------- logits = pooled @ W^T + b ----------------
__global__ __launch_bounds__(256) void logits_kernel(
    const float* __restrict__ part, const float* __restrict__ W,
    const float* __restrict__ bias, float* __restrict__ out_logits)
{
  __shared__ float p[ND];
  const int b = blockIdx.x;
  const int tid = threadIdx.x;
  for (int i = tid; i < ND; i += 256) {
    float s = 0.f;
    #pragma unroll
    for (int z = 0; z < 8; z++) s += part[(z * NB + b) * ND + i];
    p[i] = s * (1.f / NT);
  }
  __syncthreads();
  #pragma unroll
  for (int cc = 0; cc < 2; cc++) {
    const int c = tid + cc * 256;
    const float* wr = W + (size_t)c * ND;
    float s = 0.f;
    for (int k = 0; k < ND; k++) s = fmaf(p[k], wr[k], s);
    out_logits[b * NC + c] = s + bias[c];
  }
}

// ---------------- cross-entropy loss ----------------
__global__ __launch_bounds__(512) void loss_kernel(
    const float* __restrict__ logits, const int* __restrict__ labels,
    float* __restrict__ out_loss)
{
  __shared__ float red[8];
  const int tid = threadIdx.x;
  float acc = 0.f;
  for (int b = 0; b < NB; b++) {
    const float v = logits[b * NC + tid];
    float m = v;
    #pragma unroll
    for (int off = 32; off; off >>= 1) m = fmaxf(m, __shfl_xor(m, off, 64));
    if ((tid & 63) == 0) red[tid >> 6] = m;
    __syncthreads();
    m = red[0];
    #pragma unroll
    for (int w = 1; w < 8; w++) m = fmaxf(m, red[w]);
    __syncthreads();
    float e = expf(v - m);
    #pragma unroll
    for (int off = 32; off; off >>= 1) e += __shfl_xor(e, off, 64);
    if ((tid & 63) == 0) red[tid >> 6] = e;
    __syncthreads();
    if (tid == 0) {
      float s = red[0] + red[1] + red[2] + red[3] + red[4] + red[5] + red[6] + red[7];
      const int lab = labels[b];
      acc += -(logits[b * NC + lab] - m - logf(s));
    }
    __syncthreads();
  }
  if (tid == 0) out_loss[0] = acc * (1.f / NB);
}

extern "C" void kernel_launch(void* const* d_in, const int* in_sizes, int n_in,
                              void* d_out, int out_size, void* d_ws, size_t ws_size,
                              hipStream_t stream) {
  const float* F      = (const float*)d_in[0];   // features [16,2048,1024]
  const int*   labels = (const int*)  d_in[1];   // [16]
  const float* W      = (const float*)d_in[2];   // [512,1024]
  const float* bias   = (const float*)d_in[3];   // [512]

  float* out        = (float*)d_out;
  float* out_soft   = out;                                // 16777216
  float* out_raw    = out + (size_t)NM * NC;              // 16777216
  float* out_logits = out + (size_t)2 * NM * NC;          // 8192
  float* out_loss   = out_logits + (size_t)NB * NC;       // 1

  float* part = (float*)d_ws;                             // 8*16*1024 f32 = 512 KB

  hipLaunchKernelGGL(pool_partial_kernel, dim3(ND / 256, NB, 8), dim3(256), 0, stream, F, part);
  hipLaunchKernelGGL(cam_softmax_kernel, dim3(NM / BM), dim3(256), 0, stream, F, W, out_soft, out_raw);
  hipLaunchKernelGGL(logits_kernel, dim3(NB), dim3(256), 0, stream, part, W, bias, out_logits);
  hipLaunchKernelGGL(loss_kernel, dim3(1), dim3(512), 0, stream, out_logits, labels, out_loss);
}

// Round 2
// 383.137 us; speedup vs baseline: 1.5880x; 1.5880x over previous
//
#include <hip/hip_runtime.h>
#include <cstdint>

typedef __attribute__((ext_vector_type(8))) short short8;
typedef __attribute__((ext_vector_type(4))) float f32x4;

#define NB 16
#define NT 2048
#define ND 1024
#define NC 512
#define NM (NB*NT)   // 32768 rows

#define BM 64        // rows per block
#define BKS 64       // K per stage step (two 32-halves)
#define NWAVE 8      // 512 threads

__device__ __forceinline__ unsigned short f2bf(float f){
  unsigned int u = __float_as_uint(f);
  u += 0x7fffu + ((u >> 16) & 1u);   // RNE; inputs are finite normals
  return (unsigned short)(u >> 16);
}

// async 16B global -> LDS DMA (wave-uniform LDS base + lane*16)
__device__ __forceinline__ void async_copy16(const void* g, void* l) {
  __builtin_amdgcn_global_load_lds(
      (const __attribute__((address_space(1))) void*)g,
      (__attribute__((address_space(3))) void*)l,
      16, 0, 0);
}

// ---------------- CAM GEMM + fused softmax ----------------
// Block: 512 threads (8 waves). Tile: 64 rows x full C=512 (softmax in-block).
// Wave w: cols [w*64, w*64+64): ni=4, mi=4, BK=64 staged as two 32-halves.
// LDS layout (unpadded, K-major, row stride 64 B = structural-min bank pattern):
//   As elem = half*2048 + row*32 + k   (8 KB)
//   Bs elem = half*16384 + col*32 + k  (64 KB)
template<bool PRECONV>
__global__ __launch_bounds__(512, 4) void cam_softmax_kernel(
    const unsigned short* __restrict__ Fb,   // bf16 [32768,1024] (PRECONV)
    const float* __restrict__ F,             // fp32 [32768,1024] (!PRECONV)
    const unsigned short* __restrict__ Wb,   // bf16 [512,1024]
    float* __restrict__ out_soft,
    float* __restrict__ out_raw)
{
  __shared__ alignas(16) unsigned short As[2 * BM * 32];    // 8 KB
  __shared__ alignas(16) unsigned short Bs[2 * NC * 32];    // 64 KB
  __shared__ float redmax[NWAVE][BM];
  __shared__ float redsum[NWAVE][BM];

  const int tid    = threadIdx.x;
  const int wave   = tid >> 6;
  const int lane   = tid & 63;
  const int lane15 = lane & 15;
  const int quad   = lane >> 4;
  const int m0     = blockIdx.x * BM;

  f32x4 acc[4][4];
  #pragma unroll
  for (int mi = 0; mi < 4; mi++)
    #pragma unroll
    for (int ni = 0; ni < 4; ni++)
      acc[mi][ni] = (f32x4){0.f, 0.f, 0.f, 0.f};

  // staging geometry (per-lane, loop-invariant)
  const int srow = lane >> 2;          // 0..15 within a 16-row segment
  const int skoff = (lane & 3) * 8;    // 0,8,16,24 elems within 32-k half

  for (int ks = 0; ks < ND / BKS; ks++) {
    const int k0 = ks * BKS;
    // ---- stage A: seg s = wave (8 segs of 1 KB) ----
    {
      const int s = wave;
      const int row = ((s & 3) << 4) + srow;
      const int half = s >> 2;
      if (PRECONV) {
        async_copy16(Fb + (size_t)(m0 + row) * ND + k0 + half * 32 + skoff,
                     &As[s * 512]);
      }
    }
    // ---- stage B: segs s2 = wave*8 + t (64 segs of 1 KB) ----
    #pragma unroll
    for (int t = 0; t < 8; t++) {
      const int s2 = wave * 8 + t;
      const int col = ((s2 & 31) << 4) + srow;
      const int half = s2 >> 5;
      async_copy16(Wb + (size_t)col * ND + k0 + half * 32 + skoff,
                   &Bs[s2 * 512]);
    }
    if (!PRECONV) {
      // stage A from fp32 with convert: 64x64 tile = 1024 float4, 2/thread
      #pragma unroll
      for (int i = 0; i < 2; i++) {
        const int j = tid * 2 + i;
        const int row = j >> 4;
        const int kq = j & 15;           // float4 index within 64-k row
        const float4 v = *reinterpret_cast<const float4*>(
            F + (size_t)(m0 + row) * ND + k0 + kq * 4);
        ushort4 s4;
        s4.x = f2bf(v.x); s4.y = f2bf(v.y); s4.z = f2bf(v.z); s4.w = f2bf(v.w);
        *reinterpret_cast<ushort4*>(&As[(kq >> 3) * 2048 + row * 32 + (kq & 7) * 4]) = s4;
      }
    }
    __syncthreads();

    // ---- MFMA: 2 halves x (4 af + 4 bf reads, 16 MFMAs) ----
    #pragma unroll
    for (int half = 0; half < 2; half++) {
      short8 af[4];
      #pragma unroll
      for (int mi = 0; mi < 4; mi++)
        af[mi] = *reinterpret_cast<const short8*>(
            &As[half * 2048 + (mi * 16 + lane15) * 32 + quad * 8]);
      #pragma unroll
      for (int ni = 0; ni < 4; ni++) {
        const short8 bf = *reinterpret_cast<const short8*>(
            &Bs[half * 16384 + (wave * 64 + ni * 16 + lane15) * 32 + quad * 8]);
        #pragma unroll
        for (int mi = 0; mi < 4; mi++)
          acc[mi][ni] = __builtin_amdgcn_mfma_f32_16x16x32_bf16(af[mi], bf, acc[mi][ni], 0, 0, 0);
      }
    }
    __syncthreads();
  }

  // ---- epilogue: fused softmax over C=512 ----
  // C/D layout: col = lane15 (+wave*64+ni*16), row = quad*4 + reg (+mi*16)
  #pragma unroll
  for (int mi = 0; mi < 4; mi++)
    #pragma unroll
    for (int r = 0; r < 4; r++) {
      float m = acc[mi][0][r];
      #pragma unroll
      for (int ni = 1; ni < 4; ni++) m = fmaxf(m, acc[mi][ni][r]);
      #pragma unroll
      for (int off = 1; off < 16; off <<= 1) m = fmaxf(m, __shfl_xor(m, off, 64));
      if (lane15 == 0) redmax[wave][mi * 16 + quad * 4 + r] = m;
    }
  __syncthreads();

  float rsum[4][4];
  #pragma unroll
  for (int mi = 0; mi < 4; mi++)
    #pragma unroll
    for (int r = 0; r < 4; r++) {
      const int row = mi * 16 + quad * 4 + r;
      float m = redmax[0][row];
      #pragma unroll
      for (int w = 1; w < NWAVE; w++) m = fmaxf(m, redmax[w][row]);
      float s = 0.f;
      #pragma unroll
      for (int ni = 0; ni < 4; ni++) {
        const float e = __expf(acc[mi][ni][r] - m);
        acc[mi][ni][r] = e;
        s += e;
      }
      #pragma unroll
      for (int off = 1; off < 16; off <<= 1) s += __shfl_xor(s, off, 64);
      rsum[mi][r] = s;
    }
  if (lane15 == 0) {
    #pragma unroll
    for (int mi = 0; mi < 4; mi++)
      #pragma unroll
      for (int r = 0; r < 4; r++)
        redsum[wave][mi * 16 + quad * 4 + r] = rsum[mi][r];
  }
  __syncthreads();

  #pragma unroll
  for (int mi = 0; mi < 4; mi++)
    #pragma unroll
    for (int r = 0; r < 4; r++) {
      const int row = mi * 16 + quad * 4 + r;
      float s = redsum[0][row];
      #pragma unroll
      for (int w = 1; w < NWAVE; w++) s += redsum[w][row];
      const float inv = 1.f / s;
      const size_t gr = (size_t)(m0 + row) * NC;
      #pragma unroll
      for (int ni = 0; ni < 4; ni++) {
        const int col = wave * 64 + ni * 16 + lane15;
        const float v = acc[mi][ni][r] * inv;
        out_soft[gr + col] = v;
        out_raw [gr + col] = v;
      }
    }
}

// ---------------- fused convert(+pool): F fp32 -> Fb bf16, partial sums over T ----------------
// grid (32 zchunks, 16 b), 512 threads: tid covers (thalf = tid>>8, d-quad = tid&255)
template<bool WRITE_FB>
__global__ __launch_bounds__(512) void convert_pool_kernel(
    const float* __restrict__ F, unsigned short* __restrict__ Fb,
    float* __restrict__ part)    // part[32][16][1024]
{
  __shared__ float4 psum[512];
  const int tid = threadIdx.x;
  const int z = blockIdx.x;
  const int b = blockIdx.y;
  const int th = tid >> 8;              // 0/1
  const int d4 = (tid & 255) * 4;

  float4 s = (float4){0.f, 0.f, 0.f, 0.f};
  const size_t base = ((size_t)b * NT + z * 64) * ND;
  #pragma unroll 4
  for (int t = th; t < 64; t += 2) {
    const size_t idx = base + (size_t)t * ND + d4;
    const float4 v = *reinterpret_cast<const float4*>(F + idx);
    if (WRITE_FB) {
      ushort4 s4;
      s4.x = f2bf(v.x); s4.y = f2bf(v.y); s4.z = f2bf(v.z); s4.w = f2bf(v.w);
      *reinterpret_cast<ushort4*>(Fb + idx) = s4;
    }
    s.x += v.x; s.y += v.y; s.z += v.z; s.w += v.w;
  }
  psum[tid] = s;
  __syncthreads();
  if (tid < 256) {
    const float4 a = psum[tid];
    const float4 c = psum[tid + 256];
    float4 r;
    r.x = a.x + c.x; r.y = a.y + c.y; r.z = a.z + c.z; r.w = a.w + c.w;
    *reinterpret_cast<float4*>(part + (size_t)(z * NB + b) * ND + d4) = r;
  }
}

// ---------------- W fp32 -> bf16 ----------------
__global__ __launch_bounds__(256) void convw_kernel(
    const float* __restrict__ W, unsigned short* __restrict__ Wb)
{
  const size_t j = ((size_t)blockIdx.x * 256 + threadIdx.x) * 8;
  const float4 a = *reinterpret_cast<const float4*>(W + j);
  const float4 c = *reinterpret_cast<const float4*>(W + j + 4);
  ushort4 lo, hi;
  lo.x = f2bf(a.x); lo.y = f2bf(a.y); lo.z = f2bf(a.z); lo.w = f2bf(a.w);
  hi.x = f2bf(c.x); hi.y = f2bf(c.y); hi.z = f2bf(c.z); hi.w = f2bf(c.w);
  *reinterpret_cast<ushort4*>(Wb + j) = lo;
  *reinterpret_cast<ushort4*>(Wb + j + 4) = hi;
}

// ---------------- logits = pooled @ W^T + b (fp32) ----------------
__global__ __launch_bounds__(512) void logits_kernel(
    const float* __restrict__ part, const float* __restrict__ W,
    const float* __restrict__ bias, float* __restrict__ out_logits)
{
  __shared__ float p[ND];
  const int b = blockIdx.x;
  const int tid = threadIdx.x;
  for (int i = tid; i < ND; i += 512) {
    float s = 0.f;
    #pragma unroll
    for (int z = 0; z < 32; z++) s += part[(size_t)(z * NB + b) * ND + i];
    p[i] = s * (1.f / NT);
  }
  __syncthreads();
  const int c = tid;
  const float* wr = W + (size_t)c * ND;
  float s = 0.f;
  for (int k = 0; k < ND; k++) s = fmaf(p[k], wr[k], s);
  out_logits[b * NC + c] = s + bias[c];
}

// ---------------- cross-entropy loss (fp32) ----------------
__global__ __launch_bounds__(512) void loss_kernel(
    const float* __restrict__ logits, const int* __restrict__ labels,
    float* __restrict__ out_loss)
{
  __shared__ float red[8];
  const int tid = threadIdx.x;
  float acc = 0.f;
  for (int b = 0; b < NB; b++) {
    const float v = logits[b * NC + tid];
    float m = v;
    #pragma unroll
    for (int off = 32; off; off >>= 1) m = fmaxf(m, __shfl_xor(m, off, 64));
    if ((tid & 63) == 0) red[tid >> 6] = m;
    __syncthreads();
    m = red[0];
    #pragma unroll
    for (int w = 1; w < 8; w++) m = fmaxf(m, red[w]);
    __syncthreads();
    float e = expf(v - m);
    #pragma unroll
    for (int off = 32; off; off >>= 1) e += __shfl_xor(e, off, 64);
    if ((tid & 63) == 0) red[tid >> 6] = e;
    __syncthreads();
    if (tid == 0) {
      float s = red[0] + red[1] + red[2] + red[3] + red[4] + red[5] + red[6] + red[7];
      const int lab = labels[b];
      acc += -(logits[b * NC + lab] - m - logf(s));
    }
    __syncthreads();
  }
  if (tid == 0) out_loss[0] = acc * (1.f / NB);
}

extern "C" void kernel_launch(void* const* d_in, const int* in_sizes, int n_in,
                              void* d_out, int out_size, void* d_ws, size_t ws_size,
                              hipStream_t stream) {
  const float* F      = (const float*)d_in[0];   // [16,2048,1024]
  const int*   labels = (const int*)  d_in[1];   // [16]
  const float* W      = (const float*)d_in[2];   // [512,1024]
  const float* bias   = (const float*)d_in[3];   // [512]

  float* out        = (float*)d_out;
  float* out_soft   = out;
  float* out_raw    = out + (size_t)NM * NC;
  float* out_logits = out + (size_t)2 * NM * NC;
  float* out_loss   = out_logits + (size_t)NB * NC;

  // ws layout: part [0, 2 MiB) | Wb [2 MiB, 3 MiB) | Fb [4 MiB, 68 MiB)
  char* ws = (char*)d_ws;
  float* part = (float*)ws;                                     // 32*16*1024 f32
  unsigned short* Wb = (unsigned short*)(ws + (2u << 20));      // 512*1024 bf16
  unsigned short* Fb = (unsigned short*)(ws + (4u << 20));      // 32768*1024 bf16
  const bool preconv = ws_size >= (4u << 20) + (size_t)NM * ND * 2;

  if (preconv) {
    convert_pool_kernel<true><<<dim3(32, NB), 512, 0, stream>>>(F, Fb, part);
    convw_kernel<<<NC * ND / (256 * 8), 256, 0, stream>>>(W, Wb);
    cam_softmax_kernel<true><<<NM / BM, 512, 0, stream>>>(Fb, F, Wb, out_soft, out_raw);
  } else {
    convert_pool_kernel<false><<<dim3(32, NB), 512, 0, stream>>>(F, Fb, part);
    convw_kernel<<<NC * ND / (256 * 8), 256, 0, stream>>>(W, Wb);
    cam_softmax_kernel<false><<<NM / BM, 512, 0, stream>>>(Fb, F, Wb, out_soft, out_raw);
  }
  logits_kernel<<<NB, 512, 0, stream>>>(part, W, bias, out_logits);
  loss_kernel<<<1, 512, 0, stream>>>(out_logits, labels, out_loss);
}